// Round 8
// baseline (1698.057 us; speedup 1.0000x reference)
//
#include <hip/hip_runtime.h>
#include <hip/hip_bf16.h>
#include <stdint.h>

#define N_TOK 65536
#define D 1024
#define NE 16
#define MAXTILES 544

typedef __attribute__((ext_vector_type(4))) float f32x4;
typedef __attribute__((ext_vector_type(8))) short bf16x8;
typedef __attribute__((ext_vector_type(4))) unsigned short u16x4;

static __device__ __forceinline__ unsigned short f2bf(float f) {
  union { float f; uint32_t u; } c{f};
  uint32_t u = c.u;
  uint32_t r = (u + 0x7FFFu + ((u >> 16) & 1u)) >> 16;  // RNE
  return (unsigned short)r;
}
static __device__ __forceinline__ float bf2f(unsigned short h) {
  union { uint32_t u; float f; } c{((uint32_t)h) << 16};
  return c.f;
}

static __device__ __forceinline__ void gload_lds16(const void* g, void* s) {
  __builtin_amdgcn_global_load_lds(
      (const __attribute__((address_space(1))) void*)(g),
      (__attribute__((address_space(3))) void*)(s), 16, 0, 0);
}

// ---- zero the counts array (replaces hipMemsetAsync: capture region = launches only) ----
__global__ void k_zero(int* __restrict__ counts) {
  if (threadIdx.x < NE) counts[threadIdx.x] = 0;
}

// ---- split fp32 -> bf16 hi (+ optional lo residual) ----
__global__ __launch_bounds__(256) void k_split(const float* __restrict__ src,
                                               unsigned short* __restrict__ hi,
                                               unsigned short* __restrict__ lo,
                                               int n4, int use_lo) {
  int i = blockIdx.x * blockDim.x + threadIdx.x;
  int stride = gridDim.x * blockDim.x;
  for (; i < n4; i += stride) {
    f32x4 v = ((const f32x4*)src)[i];
    u16x4 h, l;
#pragma unroll
    for (int j = 0; j < 4; ++j) {
      unsigned short hb = f2bf(v[j]);
      h[j] = hb;
      if (use_lo) l[j] = f2bf(v[j] - bf2f(hb));
    }
    ((u16x4*)hi)[i] = h;
    if (use_lo) ((u16x4*)lo)[i] = l;
  }
}

// ---- gating: one wave per token-batch; lane = (expert, quarter) ----
// argmax(softmax(z)) == argmax(z): softmax never computed.
__global__ __launch_bounds__(256) void k_gate(const float* __restrict__ x,
                                              const float* __restrict__ Wg,
                                              const float* __restrict__ bg,
                                              int* __restrict__ idx,
                                              int* __restrict__ counts) {
  __shared__ int lhist[NE];
  int tid = threadIdx.x;
  if (tid < NE) lhist[tid] = 0;
  __syncthreads();
  int wave = tid >> 6, lane = tid & 63;
  int e = lane & 15, q = lane >> 4;
  const float* wrow = Wg + e * D + q * 256;
  float biase = bg[e];
#pragma unroll 1
  for (int t = 0; t < 16; ++t) {
    int n = (blockIdx.x * 4 + wave) * 16 + t;
    const float* xrow = x + (size_t)n * D + q * 256;
    float p = 0.f;
#pragma unroll 4
    for (int i = 0; i < 64; ++i) {
      f32x4 xv = *(const f32x4*)(xrow + i * 4);
      f32x4 wv = *(const f32x4*)(wrow + i * 4);
      p += xv[0] * wv[0] + xv[1] * wv[1] + xv[2] * wv[2] + xv[3] * wv[3];
    }
    p += __shfl_xor(p, 16);
    p += __shfl_xor(p, 32);
    float v = p + biase;
    int best = e;
#pragma unroll
    for (int off = 1; off < 16; off <<= 1) {
      float ov = __shfl_xor(v, off);
      int oe = __shfl_xor(best, off);
      // argmax with first-occurrence (lowest index) tie-break, like jnp.argmax
      if (ov > v || (ov == v && oe < best)) { v = ov; best = oe; }
    }
    if (lane == 0) {
      idx[n] = best;
      atomicAdd(&lhist[best], 1);
    }
  }
  __syncthreads();
  if (tid < NE) atomicAdd(&counts[tid], lhist[tid]);
}

// ---- plan: exclusive scan + row-tile table (single thread; E=16, <=528 tiles) ----
__global__ void k_plan(const int* __restrict__ counts, int* __restrict__ offsets,
                       int* __restrict__ running, int* __restrict__ tile_e,
                       int* __restrict__ tile_row, int* __restrict__ ntiles) {
  if (threadIdx.x != 0 || blockIdx.x != 0) return;
  int off = 0, nt = 0;
  for (int e = 0; e < NE; ++e) {
    offsets[e] = off;
    running[e] = off;
    int c = counts[e];
    for (int r = 0; r < c; r += 128) { tile_e[nt] = e; tile_row[nt] = off + r; ++nt; }
    off += c;
  }
  offsets[NE] = off;
  ntiles[0] = nt;
}

// ---- scatter: counting sort of token ids by expert ----
__global__ __launch_bounds__(256) void k_scatter(const int* __restrict__ idx,
                                                 int* __restrict__ running,
                                                 int* __restrict__ sorted) {
  __shared__ int cnt[NE], base[NE];
  int tid = threadIdx.x;
  if (tid < NE) cnt[tid] = 0;
  __syncthreads();
  int t = blockIdx.x * 256 + tid;
  int e = idx[t];
  int r = atomicAdd(&cnt[e], 1);
  __syncthreads();
  if (tid < NE) base[tid] = cnt[tid] ? atomicAdd(&running[tid], cnt[tid]) : 0;
  __syncthreads();
  sorted[base[e] + r] = t;
}

// ---- grouped gather-GEMM: out[tok] = x[tok] @ We[e].T + be[e], bf16 split ----
// m97 structure: 128x128 tile, BK=32, 4 waves (2x2), 4x4 frags of 16x16x32 bf16.
// TERMS==3: acc += Ah*Bh + Ah*Bl + Al*Bh  (~1e-5 abs err vs fp32)
template <int TERMS>
__global__ __launch_bounds__(256, 2) void k_moe_gemm(
    const unsigned short* __restrict__ xh, const unsigned short* __restrict__ xl,
    const unsigned short* __restrict__ Weh, const unsigned short* __restrict__ Wel,
    const float* __restrict__ be, const int* __restrict__ sorted,
    const int* __restrict__ offsets, const int* __restrict__ tile_e,
    const int* __restrict__ tile_row, const int* __restrict__ ntiles,
    float* __restrict__ out) {
  int t = blockIdx.y;
  if (t >= ntiles[0]) return;
  int e = tile_e[t];
  int row0 = tile_row[t];
  int rows = min(128, offsets[e + 1] - row0);
  int col0 = blockIdx.x * 128;

  __shared__ __align__(16) short Ah[128][32], Al[128][32], Bh[128][32], Bl[128][32];
  __shared__ int rid[128];

  int tid = threadIdx.x;
  if (tid < 128) rid[tid] = sorted[row0 + min(tid, rows - 1)];
  __syncthreads();

  int wave = tid >> 6, lane = tid & 63;
  int seg = lane & 3;    // 16B segment within a 64B row
  int rsub = lane >> 2;  // row within 16-row chunk

  int r0 = wave * 16 + rsub;  // staging rows, chunk j=0
  int r1 = 64 + r0;           // chunk j=1

  size_t offA0 = (size_t)rid[r0] * D + seg * 8;
  size_t offA1 = (size_t)rid[r1] * D + seg * 8;
  size_t offB0 = ((size_t)e * D + col0 + r0) * D + seg * 8;
  size_t offB1 = offB0 + (size_t)64 * D;

  // wave-uniform LDS chunk bases (1024B per global_load_lds: HW = base + lane*16)
  short* aB0 = &Ah[0][0] + wave * 512;
  short* aB1 = &Ah[0][0] + (4 + wave) * 512;
  short* lB0 = &Al[0][0] + wave * 512;
  short* lB1 = &Al[0][0] + (4 + wave) * 512;
  short* bB0 = &Bh[0][0] + wave * 512;
  short* bB1 = &Bh[0][0] + (4 + wave) * 512;
  short* cB0 = &Bl[0][0] + wave * 512;
  short* cB1 = &Bl[0][0] + (4 + wave) * 512;

  f32x4 acc[4][4];
#pragma unroll
  for (int m = 0; m < 4; ++m)
#pragma unroll
    for (int n = 0; n < 4; ++n) acc[m][n] = (f32x4)0.f;

  int wr = (wave >> 1) * 64, wc = (wave & 1) * 64;
  int frow = lane & 15;
  int fk = (lane >> 4) * 8;

  for (int ks = 0; ks < D; ks += 32) {
    gload_lds16(xh + offA0 + ks, aB0);
    gload_lds16(xh + offA1 + ks, aB1);
    gload_lds16(Weh + offB0 + ks, bB0);
    gload_lds16(Weh + offB1 + ks, bB1);
    if (TERMS == 3) {
      gload_lds16(xl + offA0 + ks, lB0);
      gload_lds16(xl + offA1 + ks, lB1);
      gload_lds16(Wel + offB0 + ks, cB0);
      gload_lds16(Wel + offB1 + ks, cB1);
    }
    __syncthreads();
    bf16x8 ah[4], al[4], bh[4], bl[4];
#pragma unroll
    for (int m = 0; m < 4; ++m) {
      ah[m] = *(const bf16x8*)&Ah[wr + m * 16 + frow][fk];
      if (TERMS == 3) al[m] = *(const bf16x8*)&Al[wr + m * 16 + frow][fk];
    }
#pragma unroll
    for (int n = 0; n < 4; ++n) {
      bh[n] = *(const bf16x8*)&Bh[wc + n * 16 + frow][fk];
      if (TERMS == 3) bl[n] = *(const bf16x8*)&Bl[wc + n * 16 + frow][fk];
    }
#pragma unroll
    for (int m = 0; m < 4; ++m)
#pragma unroll
      for (int n = 0; n < 4; ++n) {
        acc[m][n] = __builtin_amdgcn_mfma_f32_16x16x32_bf16(ah[m], bh[n], acc[m][n], 0, 0, 0);
        if (TERMS == 3) {
          acc[m][n] = __builtin_amdgcn_mfma_f32_16x16x32_bf16(ah[m], bl[n], acc[m][n], 0, 0, 0);
          acc[m][n] = __builtin_amdgcn_mfma_f32_16x16x32_bf16(al[m], bh[n], acc[m][n], 0, 0, 0);
        }
      }
    __syncthreads();
  }

  // epilogue: C/D mapping col=lane&15, row=(lane>>4)*4+r (verified m89/m91)
#pragma unroll
  for (int n = 0; n < 4; ++n) {
    int col = col0 + wc + n * 16 + frow;
    float bias = be[e * D + col];
#pragma unroll
    for (int m = 0; m < 4; ++m) {
#pragma unroll
      for (int r = 0; r < 4; ++r) {
        int lrow = wr + m * 16 + (lane >> 4) * 4 + r;
        if (lrow < rows) out[(size_t)rid[lrow] * D + col] = acc[m][n][r] + bias;
      }
    }
  }
}

// ---- emergency fallback (tiny ws): fully fused naive fp32, one block per token ----
__global__ __launch_bounds__(256) void k_naive(const float* __restrict__ x,
                                               const float* __restrict__ Wg,
                                               const float* __restrict__ bg,
                                               const float* __restrict__ We,
                                               const float* __restrict__ be,
                                               float* __restrict__ out) {
  int n = blockIdx.x;
  __shared__ float xs[D];
  __shared__ float red[NE];
  __shared__ int se;
  int tid = threadIdx.x;
  for (int i = tid; i < D; i += 256) xs[i] = x[(size_t)n * D + i];
  __syncthreads();
  if (tid < NE) {
    float p = 0.f;
    for (int k = 0; k < D; ++k) p += xs[k] * Wg[tid * D + k];
    red[tid] = p + bg[tid];
  }
  __syncthreads();
  if (tid == 0) {
    float bv = red[0]; int bi = 0;
    for (int e2 = 1; e2 < NE; ++e2) if (red[e2] > bv) { bv = red[e2]; bi = e2; }
    se = bi;
  }
  __syncthreads();
  int e = se;
  for (int c = tid; c < D; c += 256) {
    const float* w = We + (size_t)e * D * D + (size_t)c * D;
    float p = 0.f;
    for (int k = 0; k < D; ++k) p += xs[k] * w[k];
    out[(size_t)n * D + c] = p + be[e * D + c];
  }
}

extern "C" void kernel_launch(void* const* d_in, const int* in_sizes, int n_in,
                              void* d_out, int out_size, void* d_ws, size_t ws_size,
                              hipStream_t stream) {
  const float* x  = (const float*)d_in[0];
  const float* Wg = (const float*)d_in[1];
  const float* bg = (const float*)d_in[2];
  const float* We = (const float*)d_in[3];
  const float* be = (const float*)d_in[4];
  float* out = (float*)d_out;

  char* ws = (char*)d_ws;
  size_t p = 0;
  auto alloc = [&](size_t bytes) {
    char* r = ws + p;
    p = (p + bytes + 255) & ~(size_t)255;
    return r;
  };
  const size_t XB = (size_t)N_TOK * D * 2;       // 128 MB per bf16 copy of x
  const size_t WB = (size_t)NE * D * D * 2;      // 32 MB per bf16 copy of We
  unsigned short* xh  = (unsigned short*)alloc(XB);
  unsigned short* Weh = (unsigned short*)alloc(WB);
  int* idx      = (int*)alloc(N_TOK * 4);
  int* sorted   = (int*)alloc(N_TOK * 4);
  int* counts   = (int*)alloc(NE * 4);
  int* offsets  = (int*)alloc((NE + 1) * 4);
  int* running  = (int*)alloc(NE * 4);
  int* ntiles   = (int*)alloc(4);
  int* tile_e   = (int*)alloc(MAXTILES * 4);
  int* tile_row = (int*)alloc(MAXTILES * 4);
  size_t need1 = p;

  if (ws_size < need1) {  // no room for anything useful: naive fused fallback
    k_naive<<<N_TOK, 256, 0, stream>>>(x, Wg, bg, We, be, out);
    return;
  }

  unsigned short* xl = nullptr;
  unsigned short* Wel = nullptr;
  int use_lo = 0;
  if (ws_size >= need1 + XB + WB) {
    xl  = (unsigned short*)alloc(XB);
    Wel = (unsigned short*)alloc(WB);
    use_lo = 1;
  }

  k_zero<<<1, 64, 0, stream>>>(counts);
  k_split<<<2048, 256, 0, stream>>>(x, xh, use_lo ? xl : xh, (N_TOK * D) / 4, use_lo);
  k_split<<<1024, 256, 0, stream>>>(We, Weh, use_lo ? Wel : Weh, (NE * D * D) / 4, use_lo);
  k_gate<<<N_TOK / 64, 256, 0, stream>>>(x, Wg, bg, idx, counts);
  k_plan<<<1, 64, 0, stream>>>(counts, offsets, running, tile_e, tile_row, ntiles);
  k_scatter<<<N_TOK / 256, 256, 0, stream>>>(idx, running, sorted);

  dim3 grid(D / 128, MAXTILES);
  if (use_lo)
    k_moe_gemm<3><<<grid, 256, 0, stream>>>(xh, xl, Weh, Wel, be, sorted, offsets,
                                            tile_e, tile_row, ntiles, out);
  else
    k_moe_gemm<1><<<grid, 256, 0, stream>>>(xh, xh, Weh, Weh, be, sorted, offsets,
                                            tile_e, tile_row, ntiles, out);
}